// Round 5
// baseline (145.959 us; speedup 1.0000x reference)
//
#include <hip/hip_runtime.h>
#include <hip/hip_bf16.h>

// Problem constants (fixed by the reference).
#define N_NODES 10000
#define DEG     32
#define CH      16
#define IN_DIM  4
#define BATCH   8
#define E_EDGES (N_NODES * DEG)        // 320000
#define WI_STRIDE (E_EDGES * CH)       // 5,120,000 floats between w[i] planes
#define P_COUNT 625                    // 512*625 == E_EDGES : gather period in n
#define LX_STRIDE 36                   // 32 floats/row + 4 pad (16B-aligned)
#define OUT_FLOATS (BATCH * N_NODES * CH)   // 1,280,000

// ws float offsets
#define WS_XT 0                        // xt: (10001*32) floats = 1.28 MB
#define WS_P0 (2 * 1024 * 1024 / 4)    // partial dh=0: 5.12 MB
#define WS_P1 (8 * 1024 * 1024 / 4)    // partial dh=1: 5.12 MB

// Kernel 1: transpose/pad x[B][N][4] -> xt[N+1][B][4] (node-major, 128 B/node).
__global__ __launch_bounds__(256) void lcg_transpose(const float* __restrict__ x,
                                                     float* __restrict__ xt) {
    int t = blockIdx.x * 256 + threadIdx.x;
    if (t < BATCH * N_NODES) {
        int b = t / N_NODES;
        int node = t - b * N_NODES;
        float4 v = *(const float4*)(x + 4 * t);          // x[b][node][0..3]
        *(float4*)(xt + node * 32 + b * 4) = v;
    } else if (t < BATCH * N_NODES + 8) {
        int r = t - BATCH * N_NODES;                     // zero pad row N_NODES
        *(float4*)(xt + N_NODES * 32 + r * 4) = make_float4(0.f, 0.f, 0.f, 0.f);
    }
}

// Kernel 2: block = (p, d-half). Gather index k = (512n+16d+c) mod 320000 and
// n = p+625j share k = 512p + 16d + c. This block covers d in [16dh,16dh+16):
// edge slots edges[512p+256dh .. +256) -> 256 LDS rows (36.9 KB -> 4 blocks/CU,
// 16 waves/CU; 1250 blocks halves the tail granularity vs the 625-block shape).
// Stage B: thread (cq,j,bq) = c-quad x node-group x batch-pair; weights
// prefetched one d ahead (vmcnt never drains); partial sums to ws.
__global__ __launch_bounds__(256, 4) void lcg_main(
    const float* __restrict__ xt,     // [N+1][32]
    const int*   __restrict__ edges,  // [E]
    const float* __restrict__ w,      // [4][E][16]
    float*       __restrict__ p0,     // partial dh=0 [8][N][16]
    float*       __restrict__ p1)     // partial dh=1 [8][N][16]
{
    __shared__ float lx[256 * LX_STRIDE];   // 36864 B

    int bid = blockIdx.x;
    int p  = bid >> 1;                // 0..624
    int dh = bid & 1;                 // d-half
    int t  = threadIdx.x;

    // ---- Stage A: edges + gather into LDS (rows r=0..255 ~ s=256dh+r) ----
    {
        int sub = t & 7;              // which float4 of the 128 B node row
        int rg  = t >> 3;             // 0..31 ; rows r = rg + 32k, k<8
        const int* ep = edges + 512 * p + 256 * dh;
        int nd[8];
#pragma unroll
        for (int k = 0; k < 8; k++) nd[k] = ep[rg + 32 * k];
#pragma unroll
        for (int k = 0; k < 8; k++) {
            int r = rg + 32 * k;
            float4 v = *(const float4*)(xt + nd[k] * 32 + sub * 4);
            *(float4*)(&lx[r * LX_STRIDE + sub * 4]) = v;
        }
    }
    __syncthreads();

    // ---- Stage B ----
    int cq = t & 3;                   // c-quad (4 lanes x 16 B = full w line / j)
    int j  = (t >> 2) & 15;           // node group: n = p + 625 j
    int bq = t >> 6;                  // batch pair (wave-uniform)
    int n  = p + P_COUNT * j;

    const float* wb = w + n * (DEG * CH) + 256 * dh + 4 * cq;  // w[0][32n+16dh][4cq]
    float accA[4] = {0.f, 0.f, 0.f, 0.f};          // batch 2bq
    float accB[4] = {0.f, 0.f, 0.f, 0.f};          // batch 2bq+1

    // depth-2 prefetch of the 4 weight quads
    float4 wc0 = *(const float4*)(wb);
    float4 wc1 = *(const float4*)(wb + WI_STRIDE);
    float4 wc2 = *(const float4*)(wb + 2 * WI_STRIDE);
    float4 wc3 = *(const float4*)(wb + 3 * WI_STRIDE);

#pragma unroll 2
    for (int dl = 0; dl < 16; dl++) {
        int dn = dl < 15 ? dl + 1 : 15;            // clamped (uniform) prefetch
        float4 wn0 = *(const float4*)(wb + dn * CH);
        float4 wn1 = *(const float4*)(wb + dn * CH + WI_STRIDE);
        float4 wn2 = *(const float4*)(wb + dn * CH + 2 * WI_STRIDE);
        float4 wn3 = *(const float4*)(wb + dn * CH + 3 * WI_STRIDE);

        const float* lrow = &lx[(16 * dl + 4 * cq) * LX_STRIDE + 8 * bq];
#define CC_STEP(cc, s0, s1, s2, s3)                                            \
        {                                                                      \
            float4 xa = *(const float4*)(lrow + (cc) * LX_STRIDE);             \
            float4 xb = *(const float4*)(lrow + (cc) * LX_STRIDE + 4);         \
            accA[cc] += xa.x * (s0) + xa.y * (s1) + xa.z * (s2) + xa.w * (s3); \
            accB[cc] += xb.x * (s0) + xb.y * (s1) + xb.z * (s2) + xb.w * (s3); \
        }
        CC_STEP(0, wc0.x, wc1.x, wc2.x, wc3.x)
        CC_STEP(1, wc0.y, wc1.y, wc2.y, wc3.y)
        CC_STEP(2, wc0.z, wc1.z, wc2.z, wc3.z)
        CC_STEP(3, wc0.w, wc1.w, wc2.w, wc3.w)
#undef CC_STEP
        wc0 = wn0; wc1 = wn1; wc2 = wn2; wc3 = wn3;
    }

    float* po = dh ? p1 : p0;
    int ob = n * CH + 4 * cq;
    *(float4*)(po + (2 * bq + 0) * (N_NODES * CH) + ob) =
        make_float4(accA[0], accA[1], accA[2], accA[3]);
    *(float4*)(po + (2 * bq + 1) * (N_NODES * CH) + ob) =
        make_float4(accB[0], accB[1], accB[2], accB[3]);
}

// Kernel 3: out = p0 + p1 (fully overwrites d_out).
__global__ __launch_bounds__(256) void lcg_add(const float4* __restrict__ p0,
                                               const float4* __restrict__ p1,
                                               float4* __restrict__ o) {
    int t = blockIdx.x * 256 + threadIdx.x;    // 320000 float4s exactly
    float4 a = p0[t], b = p1[t];
    o[t] = make_float4(a.x + b.x, a.y + b.y, a.z + b.z, a.w + b.w);
}

extern "C" void kernel_launch(void* const* d_in, const int* in_sizes, int n_in,
                              void* d_out, int out_size, void* d_ws, size_t ws_size,
                              hipStream_t stream) {
    const float* x     = (const float*)d_in[0];   // [8][10000][4] f32
    const int*   edges = (const int*)d_in[1];     // [320000] int
    const float* w     = (const float*)d_in[2];   // [4][320000][16] f32
    float* out = (float*)d_out;                   // [8][10000][16] f32
    float* ws  = (float*)d_ws;
    float* xt  = ws + WS_XT;
    float* p0  = ws + WS_P0;
    float* p1  = ws + WS_P1;

    int tr_total  = BATCH * N_NODES + 8;                  // 80008
    int tr_blocks = (tr_total + 255) / 256;               // 313
    lcg_transpose<<<tr_blocks, 256, 0, stream>>>(x, xt);

    lcg_main<<<2 * P_COUNT, 256, 0, stream>>>(xt, edges, w, p0, p1);

    lcg_add<<<(OUT_FLOATS / 4) / 256, 256, 0, stream>>>(
        (const float4*)p0, (const float4*)p1, (float4*)out);
}

// Round 6
// 129.623 us; speedup vs baseline: 1.1260x; 1.1260x over previous
//
#include <hip/hip_runtime.h>
#include <hip/hip_bf16.h>

// Problem constants (fixed by the reference).
#define N_NODES 10000
#define DEG     32
#define CH      16
#define IN_DIM  4
#define BATCH   8
#define E_EDGES (N_NODES * DEG)        // 320000
#define WI_STRIDE (E_EDGES * CH)       // 5,120,000 floats between w[i] planes
#define P_COUNT 625                    // 512*625 == E_EDGES : gather period in n
#define LX_STRIDE 36                   // 32 floats/row + 4 pad (16B-aligned)

// Kernel 1: transpose/pad x[B][N][4] -> xt[N+1][B][4] (node-major, 128 B/node).
__global__ __launch_bounds__(256) void lcg_transpose(const float* __restrict__ x,
                                                     float* __restrict__ xt) {
    int t = blockIdx.x * 256 + threadIdx.x;
    if (t < BATCH * N_NODES) {
        int b = t / N_NODES;
        int node = t - b * N_NODES;
        float4 v = *(const float4*)(x + 4 * t);          // x[b][node][0..3]
        *(float4*)(xt + node * 32 + b * 4) = v;
    } else if (t < BATCH * N_NODES + 8) {
        int r = t - BATCH * N_NODES;                     // zero pad row N_NODES
        *(float4*)(xt + N_NODES * 32 + r * 4) = make_float4(0.f, 0.f, 0.f, 0.f);
    }
}

// Kernel 2: one block per p (0..624), 1024 threads = 16 waves, wave = j
// (n = p + 625*j). Gather index k = (512n+16d+c) mod 320000 = 512p + 16d + c.
// Stage A: gather 512 node-rows (128 B each, contiguous per 8-lane group) into LDS.
// Stage B: lane = c + 16*dq; per iter d = 4*ds + dq. Weight load address for
// plane i is base_i + n*512 + 64*ds + lane  -> 64 CONSECUTIVE floats per wave
// instruction (256 B, 4 contiguous lines; the r2-r5 versions scattered every
// weight instr over 16 lines 1.28 MB apart - the suspected ~40 us limiter).
// Each wave fetches exactly its own 8 KB of weights once. dq-partials reduced
// with 2 shfl_xor rounds; dq-group g stores batches {2g, 2g+1}.
__global__ __launch_bounds__(1024, 8) void lcg_main(
    const float* __restrict__ xt,     // [N+1][32]
    const int*   __restrict__ edges,  // [E]
    const float* __restrict__ w,      // [4][E][16]
    float*       __restrict__ out)    // [8][N][16]
{
    __shared__ float lx[512 * LX_STRIDE];   // 73728 B -> 2 blocks/CU, 32 waves/CU

    int p = blockIdx.x;
    int t = threadIdx.x;

    // ---- Stage A: edges + gather into LDS (rows s = 0..511) ----
    {
        int sub = t & 7;              // which float4 of the 128 B node row
        int rg  = t >> 3;             // 0..127 ; rows s = rg + 128k, k<4
        const int* ep = edges + 512 * p;
        int nd[4];
#pragma unroll
        for (int k = 0; k < 4; k++) nd[k] = ep[rg + 128 * k];
#pragma unroll
        for (int k = 0; k < 4; k++) {
            int s = rg + 128 * k;
            float4 v = *(const float4*)(xt + nd[k] * 32 + sub * 4);
            *(float4*)(&lx[s * LX_STRIDE + sub * 4]) = v;
        }
    }
    __syncthreads();

    // ---- Stage B ----
    int lane = t & 63;
    int j    = t >> 6;                // wave id = node group
    int c    = lane & 15;
    int dq   = lane >> 4;             // 0..3
    int n    = p + P_COUNT * j;

    // weight base: w[i][32n + (4ds+dq)][c] = w + i*WI_STRIDE + n*512 + 64*ds + lane
    const float* wb = w + n * (DEG * CH) + lane;

    float acc[BATCH];
#pragma unroll
    for (int b = 0; b < BATCH; b++) acc[b] = 0.0f;

    // LDS row for (d = 4ds+dq, c): s = 16d + c -> base (16dq + c)*36, step 64*36
    const float* lrow = &lx[(16 * dq + c) * LX_STRIDE];

#pragma unroll 1
    for (int ds = 0; ds < 8; ds++) {
        float w0 = wb[64 * ds];
        float w1 = wb[64 * ds + WI_STRIDE];
        float w2 = wb[64 * ds + 2 * WI_STRIDE];
        float w3 = wb[64 * ds + 3 * WI_STRIDE];
        const float* lr = lrow + ds * (64 * LX_STRIDE);
#pragma unroll
        for (int b = 0; b < BATCH; b++) {
            float4 xq = *(const float4*)(lr + 4 * b);
            acc[b] += xq.x * w0 + xq.y * w1 + xq.z * w2 + xq.w * w3;
        }
    }

    // reduce over dq groups (lanes l, l^16, l^32, l^48)
#pragma unroll
    for (int b = 0; b < BATCH; b++) {
        acc[b] += __shfl_xor(acc[b], 16, 64);
        acc[b] += __shfl_xor(acc[b], 32, 64);
    }

    // dq group g stores batches 2g, 2g+1 (16 c-lanes -> one 64 B line per b)
    int ob = n * CH + c;
    out[(2 * dq + 0) * (N_NODES * CH) + ob] = acc[2 * dq + 0];
    out[(2 * dq + 1) * (N_NODES * CH) + ob] = acc[2 * dq + 1];
}

extern "C" void kernel_launch(void* const* d_in, const int* in_sizes, int n_in,
                              void* d_out, int out_size, void* d_ws, size_t ws_size,
                              hipStream_t stream) {
    const float* x     = (const float*)d_in[0];   // [8][10000][4] f32
    const int*   edges = (const int*)d_in[1];     // [320000] int
    const float* w     = (const float*)d_in[2];   // [4][320000][16] f32
    float* out = (float*)d_out;                   // [8][10000][16] f32
    float* xt  = (float*)d_ws;                    // (10001*32) floats = 1.28 MB

    int tr_total  = BATCH * N_NODES + 8;                  // 80008
    int tr_blocks = (tr_total + 255) / 256;               // 313
    lcg_transpose<<<tr_blocks, 256, 0, stream>>>(x, xt);

    lcg_main<<<P_COUNT, 1024, 0, stream>>>(xt, edges, w, out);
}